// Round 1
// baseline (322.151 us; speedup 1.0000x reference)
//
#include <hip/hip_runtime.h>
#include <hip/hip_bf16.h>

// 2-NN: out[q] = sum of 2 smallest ||q - t||^2 over 200000 train points.
// d2 = q_sq + t_sq - 2*q.t ; top-2 depends only on s = t_sq - 2*q.t.
// Pipeline: (1) convert train/test fp32->bf16 + exact fp32 row norms,
// (2) MFMA GEMM (16x16x32 bf16) with fused per-lane top-2 of s,
// (3) shuffle-merge + per-chunk partials, (4) reduce partials.

typedef short bf16x8 __attribute__((ext_vector_type(8)));   // 8 bf16 = 4 VGPRs
typedef float f32x4 __attribute__((ext_vector_type(4)));

#define N_TRAIN 200000
#define M_QUERY 2048
#define DIMS 128
#define NCHUNK 125            // train chunks; 125 * 100 tiles * 16 pts = 200000 exactly
#define TILES_PER_CHUNK 100

__device__ __forceinline__ unsigned int bf_bits(float f) {
  // fp32 -> bf16 round-to-nearest-even (normal finite inputs only)
  unsigned int u = __float_as_uint(f);
  return (u + 0x7FFFu + ((u >> 16) & 1u)) >> 16;
}

// 8 lanes per row; each lane handles 16 contiguous floats (64B) -> coalesced.
__global__ __launch_bounds__(256) void convert_kernel(
    const float* __restrict__ src, unsigned short* __restrict__ dst,
    float* __restrict__ sq, int nrows) {
  int gtid = blockIdx.x * 256 + threadIdx.x;
  int row = gtid >> 3, sub = gtid & 7;
  if (row >= nrows) return;
  const float4* s4 = reinterpret_cast<const float4*>(src + (size_t)row * DIMS + sub * 16);
  unsigned int pk[8];
  float acc = 0.f;
#pragma unroll
  for (int i = 0; i < 4; ++i) {
    float4 v = s4[i];
    acc += v.x * v.x + v.y * v.y + v.z * v.z + v.w * v.w;
    pk[i * 2 + 0] = bf_bits(v.x) | (bf_bits(v.y) << 16);
    pk[i * 2 + 1] = bf_bits(v.z) | (bf_bits(v.w) << 16);
  }
  uint4* d4 = reinterpret_cast<uint4*>(dst + (size_t)row * DIMS + sub * 16);
  d4[0] = make_uint4(pk[0], pk[1], pk[2], pk[3]);
  d4[1] = make_uint4(pk[4], pk[5], pk[6], pk[7]);
  // fp32 row norm (exact inputs), 8-lane shuffle reduce
  acc += __shfl_xor(acc, 1);
  acc += __shfl_xor(acc, 2);
  acc += __shfl_xor(acc, 4);
  if (sub == 0) sq[row] = acc;
}

// Main: grid (NCHUNK, M/256). Block = 4 waves; wave owns 64 queries (4 m-tiles),
// streams 16 train points per step. a-frags (queries) live in registers.
__global__ __launch_bounds__(256) void knn_main(
    const unsigned short* __restrict__ tb, const unsigned short* __restrict__ qb16,
    const float* __restrict__ tsq, float* __restrict__ partials) {
  const int chunk = blockIdx.x;
  const int qblock = blockIdx.y * 256;
  const int tid = threadIdx.x;
  const int w = tid >> 6, l = tid & 63;
  const int lo = l & 15, hi = l >> 4;
  const int qw = qblock + w * 64;

  // A-fragments: lane reads Q[qw + t*16 + lo][kf*32 + hi*8 .. +8]
  bf16x8 a[4][4];
#pragma unroll
  for (int t = 0; t < 4; ++t)
#pragma unroll
    for (int kf = 0; kf < 4; ++kf)
      a[t][kf] = *reinterpret_cast<const bf16x8*>(
          qb16 + (size_t)(qw + t * 16 + lo) * DIMS + kf * 32 + hi * 8);

  const float INF = __builtin_inff();
  float b1[4][4], b2[4][4];
#pragma unroll
  for (int t = 0; t < 4; ++t)
#pragma unroll
    for (int r = 0; r < 4; ++r) { b1[t][r] = INF; b2[t][r] = INF; }

  const int tile0 = chunk * TILES_PER_CHUNK;
  const unsigned short* tptr = tb + (size_t)(tile0 * 16 + lo) * DIMS + hi * 8;
  const float* tsp = tsq + tile0 * 16 + lo;
  const f32x4 zacc = {0.f, 0.f, 0.f, 0.f};

  for (int g = 0; g < TILES_PER_CHUNK; ++g) {
    bf16x8 bfr[4];
#pragma unroll
    for (int kf = 0; kf < 4; ++kf)
      bfr[kf] = *reinterpret_cast<const bf16x8*>(tptr + kf * 32);
    float tv = *tsp;

    f32x4 accv[4];
#pragma unroll
    for (int t = 0; t < 4; ++t) {
      accv[t] = __builtin_amdgcn_mfma_f32_16x16x32_bf16(a[t][0], bfr[0], zacc, 0, 0, 0);
#pragma unroll
      for (int kf = 1; kf < 4; ++kf)
        accv[t] = __builtin_amdgcn_mfma_f32_16x16x32_bf16(a[t][kf], bfr[kf], accv[t], 0, 0, 0);
    }
    // top-2 update: 3 VALU per element (fma, min, med3)
#pragma unroll
    for (int t = 0; t < 4; ++t)
#pragma unroll
      for (int r = 0; r < 4; ++r) {
        float s = fmaf(-2.f, accv[t][r], tv);
        float nb1 = fminf(b1[t][r], s);
        float nb2 = __builtin_amdgcn_fmed3f(b1[t][r], b2[t][r], s);
        b1[t][r] = nb1;
        b2[t][r] = nb2;
      }
    tptr += 16 * DIMS;
    tsp += 16;
  }

  // merge top-2 across the 16 lanes (columns) sharing each query
#pragma unroll
  for (int t = 0; t < 4; ++t)
#pragma unroll
    for (int r = 0; r < 4; ++r) {
      float v1 = b1[t][r], v2 = b2[t][r];
#pragma unroll
      for (int m = 1; m < 16; m <<= 1) {
        float o1 = __shfl_xor(v1, m);
        float o2 = __shfl_xor(v2, m);
        float n1 = fminf(v1, o1);
        float n2 = fminf(fmaxf(v1, o1), fminf(v2, o2));
        v1 = n1;
        v2 = n2;
      }
      b1[t][r] = v1;
      b2[t][r] = v2;
    }
  if (lo == 0) {
#pragma unroll
    for (int t = 0; t < 4; ++t)
#pragma unroll
      for (int r = 0; r < 4; ++r) {
        int q = qw + t * 16 + hi * 4 + r;
        float* p = partials + ((size_t)chunk * M_QUERY + q) * 2;
        p[0] = b1[t][r];
        p[1] = b2[t][r];
      }
  }
}

__global__ __launch_bounds__(256) void knn_reduce(
    const float* __restrict__ partials, const float* __restrict__ qsq,
    float* __restrict__ out) {
  int q = blockIdx.x * 256 + threadIdx.x;
  if (q >= M_QUERY) return;
  const float INF = __builtin_inff();
  float b1 = INF, b2 = INF;
  for (int c = 0; c < NCHUNK; ++c) {
    const float* p = partials + ((size_t)c * M_QUERY + q) * 2;
    float v = p[0];
    float n1 = fminf(b1, v);
    float n2 = __builtin_amdgcn_fmed3f(b1, b2, v);
    b1 = n1; b2 = n2;
    v = p[1];
    n1 = fminf(b1, v);
    n2 = __builtin_amdgcn_fmed3f(b1, b2, v);
    b1 = n1; b2 = n2;
  }
  out[q] = 2.f * qsq[q] + b1 + b2;
}

extern "C" void kernel_launch(void* const* d_in, const int* in_sizes, int n_in,
                              void* d_out, int out_size, void* d_ws, size_t ws_size,
                              hipStream_t stream) {
  const float* train = (const float*)d_in[0];  // 200000 x 128 f32
  const float* test  = (const float*)d_in[1];  // 2048 x 128 f32
  float* out = (float*)d_out;                  // 2048 f32
  char* ws = (char*)d_ws;

  size_t off_tb  = 0;                                      // train bf16: 51,200,000 B
  size_t off_qb  = off_tb  + (size_t)N_TRAIN * DIMS * 2;   // query bf16: 524,288 B
  size_t off_tsq = off_qb  + (size_t)M_QUERY * DIMS * 2;   // t_sq: 800,000 B
  size_t off_qsq = off_tsq + (size_t)N_TRAIN * 4;          // q_sq: 8,192 B
  size_t off_pt  = off_qsq + (size_t)M_QUERY * 4;          // partials: 2,048,000 B
  size_t total   = off_pt  + (size_t)NCHUNK * M_QUERY * 2 * 4;
  if (ws_size < total) return;  // ws too small: fail visibly rather than corrupt

  unsigned short* tb  = (unsigned short*)(ws + off_tb);
  unsigned short* qb  = (unsigned short*)(ws + off_qb);
  float* tsq = (float*)(ws + off_tsq);
  float* qsq = (float*)(ws + off_qsq);
  float* part = (float*)(ws + off_pt);

  hipLaunchKernelGGL(convert_kernel, dim3((N_TRAIN * 8) / 256), dim3(256), 0, stream,
                     train, tb, tsq, N_TRAIN);
  hipLaunchKernelGGL(convert_kernel, dim3((M_QUERY * 8) / 256), dim3(256), 0, stream,
                     test, qb, qsq, M_QUERY);
  hipLaunchKernelGGL(knn_main, dim3(NCHUNK, M_QUERY / 256), dim3(256), 0, stream,
                     tb, qb, tsq, part);
  hipLaunchKernelGGL(knn_reduce, dim3(M_QUERY / 256), dim3(256), 0, stream,
                     part, qsq, out);
}

// Round 2
// 170.047 us; speedup vs baseline: 1.8945x; 1.8945x over previous
//
#include <hip/hip_runtime.h>
#include <hip/hip_bf16.h>

// 2-NN: out[q] = sum of 2 smallest ||q - t||^2 over 200000 train points.
// d2 = q_sq + t_sq - 2*q.t ; top-2 depends only on s = t_sq - 2*q.t.
// Pipeline: (1) convert train/test fp32->bf16 + exact fp32 row norms,
// (2) MFMA GEMM (16x16x32 bf16), train tile staged in LDS (XOR-swizzled,
//     double-buffered, 1 barrier/iter) with fused per-lane top-2 of s,
// (3) shuffle-merge + per-chunk partials, (4) reduce partials.

typedef short bf16x8 __attribute__((ext_vector_type(8)));   // 8 bf16 = 4 VGPRs
typedef float f32x4 __attribute__((ext_vector_type(4)));

#define N_TRAIN 200000
#define M_QUERY 2048
#define DIMS 128
#define NCHUNK 125
#define PTS_PER_CHUNK 1600        // 125 * 1600 = 200000
#define TB 32                     // train points per pipeline tile (8 KB)
#define ITERS (PTS_PER_CHUNK / TB)  // 50

__device__ __forceinline__ unsigned int bf_bits(float f) {
  unsigned int u = __float_as_uint(f);
  return (u + 0x7FFFu + ((u >> 16) & 1u)) >> 16;
}

// 8 lanes per row; each lane handles 16 contiguous floats (64B) -> coalesced.
__global__ __launch_bounds__(256) void convert_kernel(
    const float* __restrict__ src, unsigned short* __restrict__ dst,
    float* __restrict__ sq, int nrows) {
  int gtid = blockIdx.x * 256 + threadIdx.x;
  int row = gtid >> 3, sub = gtid & 7;
  if (row >= nrows) return;
  const float4* s4 = reinterpret_cast<const float4*>(src + (size_t)row * DIMS + sub * 16);
  unsigned int pk[8];
  float acc = 0.f;
#pragma unroll
  for (int i = 0; i < 4; ++i) {
    float4 v = s4[i];
    acc += v.x * v.x + v.y * v.y + v.z * v.z + v.w * v.w;
    pk[i * 2 + 0] = bf_bits(v.x) | (bf_bits(v.y) << 16);
    pk[i * 2 + 1] = bf_bits(v.z) | (bf_bits(v.w) << 16);
  }
  uint4* d4 = reinterpret_cast<uint4*>(dst + (size_t)row * DIMS + sub * 16);
  d4[0] = make_uint4(pk[0], pk[1], pk[2], pk[3]);
  d4[1] = make_uint4(pk[4], pk[5], pk[6], pk[7]);
  acc += __shfl_xor(acc, 1);
  acc += __shfl_xor(acc, 2);
  acc += __shfl_xor(acc, 4);
  if (sub == 0) sq[row] = acc;
}

// Main: grid (NCHUNK, M/256). Block = 4 waves; wave owns 64 queries (4 m-tiles).
// Train tile (32 pts) staged in LDS once per block, double-buffered.
__global__ __launch_bounds__(256) void knn_main(
    const unsigned short* __restrict__ tb, const unsigned short* __restrict__ qb16,
    const float* __restrict__ tsq, float* __restrict__ partials) {
  const int chunk = blockIdx.x;
  const int qblock = blockIdx.y * 256;
  const int tid = threadIdx.x;
  const int w = tid >> 6, l = tid & 63;
  const int lo = l & 15, hi = l >> 4;
  const int qw = qblock + w * 64;

  __shared__ uint4 smem4[2][512];           // 2 x 8 KB
  char* smem = reinterpret_cast<char*>(smem4);

  // A-fragments: lane reads Q[qw + t*16 + lo][kf*32 + hi*8 .. +8]
  bf16x8 a[4][4];
#pragma unroll
  for (int t = 0; t < 4; ++t)
#pragma unroll
    for (int kf = 0; kf < 4; ++kf)
      a[t][kf] = *reinterpret_cast<const bf16x8*>(
          qb16 + (size_t)(qw + t * 16 + lo) * DIMS + kf * 32 + hi * 8);

  // Staging: thread covers tile bytes [tid*16, +16) and [tid*16+4096, +16).
  // LDS dest is XOR-swizzled: 16B-block index ^= (row & 7). Rows 16 apart share
  // (row&7), so the +4096 half uses the same swizzled offset +4096.
  const int srow = tid >> 4, sblk = tid & 15;
  const int wo = srow * 256 + (((sblk ^ (srow & 7)) << 4));
  const char* gsrc = reinterpret_cast<const char*>(tb) +
                     (size_t)chunk * PTS_PER_CHUNK * 256 + tid * 16;

  // ds_read offsets: B-frag for point p = nt*16+lo, 16B-block kb = kf*4+hi,
  // addr = p*256 + ((kb ^ (p&7)) << 4); nt adds 4096 (same swizzle).
  int roff[4];
#pragma unroll
  for (int kf = 0; kf < 4; ++kf)
    roff[kf] = lo * 256 + ((((kf << 2) + hi) ^ (lo & 7)) << 4);

  const float* tsp = tsq + chunk * PTS_PER_CHUNK + lo;

  const float INF = __builtin_inff();
  float best1[4][4], best2[4][4];
#pragma unroll
  for (int t = 0; t < 4; ++t)
#pragma unroll
    for (int r = 0; r < 4; ++r) { best1[t][r] = INF; best2[t][r] = INF; }

  // prologue: stage tile 0 into buffer 0
  {
    uint4 r0 = *reinterpret_cast<const uint4*>(gsrc);
    uint4 r1 = *reinterpret_cast<const uint4*>(gsrc + 4096);
    *reinterpret_cast<uint4*>(smem + wo) = r0;
    *reinterpret_cast<uint4*>(smem + wo + 4096) = r1;
    gsrc += TB * 256;
  }
  __syncthreads();

  const f32x4 z = {0.f, 0.f, 0.f, 0.f};
  int cur = 0;
  for (int it = 0; it < ITERS; ++it) {
    const bool pf = (it + 1 < ITERS);
    uint4 r0, r1;
    if (pf) {  // issue next tile's global loads early; latency hides under MFMA
      r0 = *reinterpret_cast<const uint4*>(gsrc);
      r1 = *reinterpret_cast<const uint4*>(gsrc + 4096);
      gsrc += TB * 256;
    }
    float tv0 = tsp[0];
    float tv1 = tsp[16];
    tsp += TB;

    const char* buf = smem + cur * 8192;
    bf16x8 f0[4], f1[4];
#pragma unroll
    for (int kf = 0; kf < 4; ++kf) {
      f0[kf] = *reinterpret_cast<const bf16x8*>(buf + roff[kf]);
      f1[kf] = *reinterpret_cast<const bf16x8*>(buf + roff[kf] + 4096);
    }

#pragma unroll
    for (int t = 0; t < 4; ++t) {
      f32x4 acc0 = __builtin_amdgcn_mfma_f32_16x16x32_bf16(a[t][0], f0[0], z, 0, 0, 0);
      f32x4 acc1 = __builtin_amdgcn_mfma_f32_16x16x32_bf16(a[t][0], f1[0], z, 0, 0, 0);
#pragma unroll
      for (int kf = 1; kf < 4; ++kf) {
        acc0 = __builtin_amdgcn_mfma_f32_16x16x32_bf16(a[t][kf], f0[kf], acc0, 0, 0, 0);
        acc1 = __builtin_amdgcn_mfma_f32_16x16x32_bf16(a[t][kf], f1[kf], acc1, 0, 0, 0);
      }
#pragma unroll
      for (int r = 0; r < 4; ++r) {
        float s0 = fmaf(-2.f, acc0[r], tv0);
        float n1 = fminf(best1[t][r], s0);
        float n2 = __builtin_amdgcn_fmed3f(best1[t][r], best2[t][r], s0);
        best1[t][r] = n1; best2[t][r] = n2;
        float s1 = fmaf(-2.f, acc1[r], tv1);
        n1 = fminf(best1[t][r], s1);
        n2 = __builtin_amdgcn_fmed3f(best1[t][r], best2[t][r], s1);
        best1[t][r] = n1; best2[t][r] = n2;
      }
    }

    if (pf) {  // write prefetched tile into the other buffer (no reads there this iter)
      char* nb = smem + (cur ^ 1) * 8192;
      *reinterpret_cast<uint4*>(nb + wo) = r0;
      *reinterpret_cast<uint4*>(nb + wo + 4096) = r1;
    }
    __syncthreads();
    cur ^= 1;
  }

  // merge top-2 across the 16 lanes (columns) sharing each query
#pragma unroll
  for (int t = 0; t < 4; ++t)
#pragma unroll
    for (int r = 0; r < 4; ++r) {
      float v1 = best1[t][r], v2 = best2[t][r];
#pragma unroll
      for (int m = 1; m < 16; m <<= 1) {
        float o1 = __shfl_xor(v1, m);
        float o2 = __shfl_xor(v2, m);
        float n1 = fminf(v1, o1);
        float n2 = fminf(fmaxf(v1, o1), fminf(v2, o2));
        v1 = n1;
        v2 = n2;
      }
      best1[t][r] = v1;
      best2[t][r] = v2;
    }
  if (lo == 0) {
#pragma unroll
    for (int t = 0; t < 4; ++t)
#pragma unroll
      for (int r = 0; r < 4; ++r) {
        int q = qw + t * 16 + hi * 4 + r;
        float* p = partials + ((size_t)chunk * M_QUERY + q) * 2;
        p[0] = best1[t][r];
        p[1] = best2[t][r];
      }
  }
}

__global__ __launch_bounds__(256) void knn_reduce(
    const float* __restrict__ partials, const float* __restrict__ qsq,
    float* __restrict__ out) {
  int q = blockIdx.x * 256 + threadIdx.x;
  if (q >= M_QUERY) return;
  const float INF = __builtin_inff();
  float b1 = INF, b2 = INF;
  for (int c = 0; c < NCHUNK; ++c) {
    const float* p = partials + ((size_t)c * M_QUERY + q) * 2;
    float v = p[0];
    float n1 = fminf(b1, v);
    float n2 = __builtin_amdgcn_fmed3f(b1, b2, v);
    b1 = n1; b2 = n2;
    v = p[1];
    n1 = fminf(b1, v);
    n2 = __builtin_amdgcn_fmed3f(b1, b2, v);
    b1 = n1; b2 = n2;
  }
  out[q] = 2.f * qsq[q] + b1 + b2;
}

extern "C" void kernel_launch(void* const* d_in, const int* in_sizes, int n_in,
                              void* d_out, int out_size, void* d_ws, size_t ws_size,
                              hipStream_t stream) {
  const float* train = (const float*)d_in[0];  // 200000 x 128 f32
  const float* test  = (const float*)d_in[1];  // 2048 x 128 f32
  float* out = (float*)d_out;                  // 2048 f32
  char* ws = (char*)d_ws;

  size_t off_tb  = 0;                                      // train bf16: 51,200,000 B
  size_t off_qb  = off_tb  + (size_t)N_TRAIN * DIMS * 2;   // query bf16
  size_t off_tsq = off_qb  + (size_t)M_QUERY * DIMS * 2;   // t_sq
  size_t off_qsq = off_tsq + (size_t)N_TRAIN * 4;          // q_sq
  size_t off_pt  = off_qsq + (size_t)M_QUERY * 4;          // partials
  size_t total   = off_pt  + (size_t)NCHUNK * M_QUERY * 2 * 4;
  if (ws_size < total) return;

  unsigned short* tbp = (unsigned short*)(ws + off_tb);
  unsigned short* qb  = (unsigned short*)(ws + off_qb);
  float* tsq = (float*)(ws + off_tsq);
  float* qsq = (float*)(ws + off_qsq);
  float* part = (float*)(ws + off_pt);

  hipLaunchKernelGGL(convert_kernel, dim3((N_TRAIN * 8) / 256), dim3(256), 0, stream,
                     train, tbp, tsq, N_TRAIN);
  hipLaunchKernelGGL(convert_kernel, dim3((M_QUERY * 8) / 256), dim3(256), 0, stream,
                     test, qb, qsq, M_QUERY);
  hipLaunchKernelGGL(knn_main, dim3(NCHUNK, M_QUERY / 256), dim3(256), 0, stream,
                     tbp, qb, tsq, part);
  hipLaunchKernelGGL(knn_reduce, dim3(M_QUERY / 256), dim3(256), 0, stream,
                     part, qsq, out);
}